// Round 17
// baseline (34.646 us; speedup 1.0000x reference)
//
#include <hip/hip_runtime.h>
#include <math.h>

#define DIMS 512
#define BATCH 1024
#define CLS 256
#define ROWS (BATCH + CLS)   // 1280 stacked rows: [f_norm; w_norm]

#define EPS_PD 1e-6f
#define DEPS2 (512.0f * 1e-6f * 1e-6f)   // D * eps^2
#define EPS_NORM 1e-12f

typedef short bf16x8 __attribute__((ext_vector_type(8)));
typedef float f32x4 __attribute__((ext_vector_type(4)));

__device__ __forceinline__ float waveReduceSum(float v) {
#pragma unroll
  for (int off = 32; off > 0; off >>= 1)
    v += __shfl_xor(v, off, 64);
  return v;
}

__device__ __forceinline__ unsigned short f2bf(float x) {
  unsigned int u = __float_as_uint(x);
  u += 0x7fffu + ((u >> 16) & 1u);
  return (unsigned short)(u >> 16);
}

// K1: grid = 1344 x 64 threads.
//  blocks 0..1279  : normalize row b (feat or w) -> fnw[b][512] bf16, Srow[b].
//  blocks 1280..1343: protoc tile t = b-1280 of the 256x256 w-Gram.
//    Self-contained: re-normalize the tile's 64 w rows from raw fp32 (two-pass,
//    fragment-order reads), MFMA the 32x32 tile, fused dist-sum -> partial[t].
//    No dependency on the norm blocks (deterministic, no atomics).
__global__ __launch_bounds__(64) void k_norm_protoc(
    const float* __restrict__ feat, const float* __restrict__ wt,
    unsigned short* __restrict__ fnw, float* __restrict__ Srow,
    float* __restrict__ partial) {
  const int b = blockIdx.x;
  const int lane = threadIdx.x;

  if (b < ROWS) {
    // ---- norm block (R7-verified body) ----
    const float* src = (b < BATCH) ? (feat + (size_t)b * DIMS)
                                   : (wt + (size_t)(b - BATCH) * DIMS);
    const float4* s4 = (const float4*)src;
    float4 a = s4[lane];
    float4 c = s4[lane + 64];

    float ss = a.x*a.x + a.y*a.y + a.z*a.z + a.w*a.w
             + c.x*c.x + c.y*c.y + c.z*c.z + c.w*c.w;
    float sm = a.x + a.y + a.z + a.w + c.x + c.y + c.z + c.w;
    ss = waveReduceSum(ss);
    sm = waveReduceSum(sm);
    const float rn = 1.f / fmaxf(sqrtf(ss), EPS_NORM);

    ushort4 pa, pc;
    pa.x = f2bf(a.x * rn); pa.y = f2bf(a.y * rn);
    pa.z = f2bf(a.z * rn); pa.w = f2bf(a.w * rn);
    pc.x = f2bf(c.x * rn); pc.y = f2bf(c.y * rn);
    pc.z = f2bf(c.z * rn); pc.w = f2bf(c.w * rn);

    ushort4* dst = (ushort4*)(fnw + (size_t)b * DIMS);
    dst[lane] = pa;
    dst[lane + 64] = pc;
    if (lane == 0) Srow[b] = sm * rn;
    return;
  }

  // ---- protoc tile block ----
  const int t = b - ROWS;                  // 0..63
  const int i0 = (t >> 3) * 32;
  const int j0 = (t & 7) * 32;
  const int lr = lane & 15;                // fragment row within 16
  const int ks = (lane >> 4) * 8;          // k sub-slice base

  // rows this lane holds: a0 = i0+lr, a1 = i0+16+lr, b0 = j0+lr, b1 = j0+16+lr
  const float* wr0 = wt + (size_t)(i0 + lr) * DIMS + ks;
  const float* wr1 = wt + (size_t)(i0 + 16 + lr) * DIMS + ks;
  const float* wr2 = wt + (size_t)(j0 + lr) * DIMS + ks;
  const float* wr3 = wt + (size_t)(j0 + 16 + lr) * DIMS + ks;
  const float* wr[4] = {wr0, wr1, wr2, wr3};

  // Pass 1: per-row sum of squares and sum (this lane's 128 elems of each row).
  float ss[4] = {0.f, 0.f, 0.f, 0.f};
  float sm[4] = {0.f, 0.f, 0.f, 0.f};
#pragma unroll
  for (int k0 = 0; k0 < 16; ++k0) {
#pragma unroll
    for (int rr = 0; rr < 4; ++rr) {
      const float4 x = *(const float4*)(wr[rr] + k0 * 32);
      const float4 y = *(const float4*)(wr[rr] + k0 * 32 + 4);
      ss[rr] += x.x*x.x + x.y*x.y + x.z*x.z + x.w*x.w
              + y.x*y.x + y.y*y.y + y.z*y.z + y.w*y.w;
      sm[rr] += x.x + x.y + x.z + x.w + y.x + y.y + y.z + y.w;
    }
  }
  // Reduce across the 4 lanes sharing each row (l, l^16, l^32, l^48).
  float rn[4], S[4];
#pragma unroll
  for (int rr = 0; rr < 4; ++rr) {
    float s2 = ss[rr];
    s2 += __shfl_xor(s2, 16, 64);
    s2 += __shfl_xor(s2, 32, 64);
    float s1 = sm[rr];
    s1 += __shfl_xor(s1, 16, 64);
    s1 += __shfl_xor(s1, 32, 64);
    rn[rr] = 1.f / fmaxf(sqrtf(s2), EPS_NORM);
    S[rr] = s1 * rn[rr];
  }

  // Pass 2: reload, normalize, bf16-round, MFMA.
  f32x4 acc00 = {0.f,0.f,0.f,0.f}, acc01 = {0.f,0.f,0.f,0.f};
  f32x4 acc10 = {0.f,0.f,0.f,0.f}, acc11 = {0.f,0.f,0.f,0.f};
#pragma unroll
  for (int k0 = 0; k0 < 16; ++k0) {
    bf16x8 fr[4];
#pragma unroll
    for (int rr = 0; rr < 4; ++rr) {
      const float4 x = *(const float4*)(wr[rr] + k0 * 32);
      const float4 y = *(const float4*)(wr[rr] + k0 * 32 + 4);
      bf16x8 f;
      f[0] = (short)f2bf(x.x * rn[rr]); f[1] = (short)f2bf(x.y * rn[rr]);
      f[2] = (short)f2bf(x.z * rn[rr]); f[3] = (short)f2bf(x.w * rn[rr]);
      f[4] = (short)f2bf(y.x * rn[rr]); f[5] = (short)f2bf(y.y * rn[rr]);
      f[6] = (short)f2bf(y.z * rn[rr]); f[7] = (short)f2bf(y.w * rn[rr]);
      fr[rr] = f;
    }
    acc00 = __builtin_amdgcn_mfma_f32_16x16x32_bf16(fr[0], fr[2], acc00, 0, 0, 0);
    acc01 = __builtin_amdgcn_mfma_f32_16x16x32_bf16(fr[0], fr[3], acc01, 0, 0, 0);
    acc10 = __builtin_amdgcn_mfma_f32_16x16x32_bf16(fr[1], fr[2], acc10, 0, 0, 0);
    acc11 = __builtin_amdgcn_mfma_f32_16x16x32_bf16(fr[1], fr[3], acc11, 0, 0, 0);
  }

  // Fused dist-sum epilogue. C/D: col = lane&15, row = (lane>>4)*4 + q.
  const int crow = (lane >> 4) * 4;
  const int ccol = lane & 15;
  const float swj0 = S[2];                 // row j0+ccol (this lane's b0 row)
  const float swj1 = S[3];                 // row j0+16+ccol
  const f32x4 accs[4] = {acc00, acc01, acc10, acc11};

  float s = 0.f;
#pragma unroll
  for (int hi = 0; hi < 2; ++hi) {
#pragma unroll
    for (int q = 0; q < 4; ++q) {
      const int i = i0 + hi * 16 + crow + q;
      // S of row i0+hi*16+crow+q lives in lane (crow+q) of S[hi]
      const float swi = __shfl(hi ? S[1] : S[0], crow + q, 64);
#pragma unroll
      for (int hj = 0; hj < 2; ++hj) {
        const int j = j0 + hj * 16 + ccol;
        const float dot = accs[hi * 2 + hj][q];
        const float swj = hj ? swj1 : swj0;
        float dist;
        if (i == j) {
          dist = sqrtf(DEPS2);             // exact self-distance
        } else {
          const float d2 = 2.f - 2.f * dot + 2.f * EPS_PD * (swi - swj) + DEPS2;
          dist = sqrtf(fmaxf(d2, 0.f));
        }
        s += dist;
      }
    }
  }
  s = waveReduceSum(s);
  if (lane == 0) partial[t] = s;
}

// K2: main GEMM + fully fused epilogue (R8-verified). grid (32,8) x 64 threads,
// one 32x32 tile per wave. Sums the 64 protoc partials in-wave; writes out
// directly from MFMA accumulators.
__global__ __launch_bounds__(64) void k_main(
    const unsigned short* __restrict__ fnw, const float* __restrict__ Srow,
    const float* __restrict__ partial, const float* __restrict__ dscale,
    const int* __restrict__ use_ds, float* __restrict__ out) {
  const int lane = threadIdx.x;
  const int r0 = blockIdx.x * 32;          // feature rows
  const int j0 = blockIdx.y * 32;          // classes

  const float myPartial = partial[lane];   // 64 entries; reduce after MFMA loop

  const int lm = lane & 15;
  const int lk = (lane >> 4) * 8;

  const unsigned short* arow0 = fnw + (size_t)(r0 + lm) * DIMS + lk;
  const unsigned short* arow1 = fnw + (size_t)(r0 + 16 + lm) * DIMS + lk;
  const unsigned short* brow0 = fnw + (size_t)(BATCH + j0 + lm) * DIMS + lk;
  const unsigned short* brow1 = fnw + (size_t)(BATCH + j0 + 16 + lm) * DIMS + lk;

  f32x4 acc00 = {0.f,0.f,0.f,0.f}, acc01 = {0.f,0.f,0.f,0.f};
  f32x4 acc10 = {0.f,0.f,0.f,0.f}, acc11 = {0.f,0.f,0.f,0.f};

#pragma unroll
  for (int k0 = 0; k0 < DIMS; k0 += 32) {
    const bf16x8 a0 = *(const bf16x8*)(arow0 + k0);
    const bf16x8 a1 = *(const bf16x8*)(arow1 + k0);
    const bf16x8 b0 = *(const bf16x8*)(brow0 + k0);
    const bf16x8 b1 = *(const bf16x8*)(brow1 + k0);
    acc00 = __builtin_amdgcn_mfma_f32_16x16x32_bf16(a0, b0, acc00, 0, 0, 0);
    acc01 = __builtin_amdgcn_mfma_f32_16x16x32_bf16(a0, b1, acc01, 0, 0, 0);
    acc10 = __builtin_amdgcn_mfma_f32_16x16x32_bf16(a1, b0, acc10, 0, 0, 0);
    acc11 = __builtin_amdgcn_mfma_f32_16x16x32_bf16(a1, b1, acc11, 0, 0, 0);
  }

  const float Sg = waveReduceSum(myPartial);
  const float Ssc = 0.1f * Sg;
  const float sc = (use_ds[0] != 0) ? fabsf(dscale[0]) : 1.0f;

  const int crow = (lane >> 4) * 4;
  const int ccol = lane & 15;
  const float swj0 = Srow[BATCH + j0 + ccol];
  const float swj1 = Srow[BATCH + j0 + 16 + ccol];
  const f32x4 accs[4] = {acc00, acc01, acc10, acc11};

#pragma unroll
  for (int hi = 0; hi < 2; ++hi) {
#pragma unroll
    for (int q = 0; q < 4; ++q) {
      const int i = r0 + hi * 16 + crow + q;
      const float sfi = Srow[i];
#pragma unroll
      for (int hj = 0; hj < 2; ++hj) {
        const int j = j0 + hj * 16 + ccol;
        const float dot = accs[hi * 2 + hj][q];
        const float swj = hj ? swj1 : swj0;
        const float d2 = 2.f - 2.f * dot + 2.f * EPS_PD * (sfi - swj) + DEPS2;
        const float dist = sqrtf(fmaxf(d2, 0.f));
        out[(size_t)i * CLS + j] = (Ssc - dist) * sc;
      }
    }
  }
}

extern "C" void kernel_launch(void* const* d_in, const int* in_sizes, int n_in,
                              void* d_out, int out_size, void* d_ws, size_t ws_size,
                              hipStream_t stream) {
  const float* feat = (const float*)d_in[0];     // [1024,512]
  const float* wt   = (const float*)d_in[1];     // [256,512]
  const float* ds   = (const float*)d_in[2];     // [1]
  const int*   use  = (const int*)d_in[3];       // scalar
  float* out = (float*)d_out;                    // [1024,256] fp32

  // ws layout: fnw bf16 1280*512*2 = 1,310,720 B ; Srow 1280 f ; partial 64 f
  unsigned short* fnw = (unsigned short*)d_ws;
  float* fbase   = (float*)((char*)d_ws + (size_t)ROWS * DIMS * 2);
  float* Srow    = fbase;
  float* partial = fbase + ROWS;

  k_norm_protoc<<<ROWS + 64, 64, 0, stream>>>(feat, wt, fnw, Srow, partial);
  k_main<<<dim3(32, 8), 64, 0, stream>>>(fnw, Srow, partial, ds, use, out);
}

// Round 18
// 20.769 us; speedup vs baseline: 1.6682x; 1.6682x over previous
//
#include <hip/hip_runtime.h>
#include <math.h>

#define DIMS 512
#define BATCH 1024
#define CLS 256
#define ROWS (BATCH + CLS)   // 1280 stacked rows: [f_norm; w_norm]

#define EPS_PD 1e-6f
#define DEPS2 (512.0f * 1e-6f * 1e-6f)   // D * eps^2
#define EPS_NORM 1e-12f

typedef short bf16x8 __attribute__((ext_vector_type(8)));   // 8 bf16 = 4 VGPRs
typedef float f32x4 __attribute__((ext_vector_type(4)));

__device__ __forceinline__ float waveReduceSum(float v) {
#pragma unroll
  for (int off = 32; off > 0; off >>= 1)
    v += __shfl_xor(v, off, 64);
  return v;
}

// round-to-nearest-even float -> bf16 (inputs are normal floats; NaN not expected)
__device__ __forceinline__ unsigned short f2bf(float x) {
  unsigned int u = __float_as_uint(x);
  u += 0x7fffu + ((u >> 16) & 1u);
  return (unsigned short)(u >> 16);
}

// K1: grid = 1280, block = 64. Row r<1024 -> feat, else weight row r-1024.
// Normalize row, cast to bf16 into fnw[r][512]; Srow[r] = sum of normalized comps.
__global__ __launch_bounds__(64) void k_norm(
    const float* __restrict__ feat, const float* __restrict__ wt,
    unsigned short* __restrict__ fnw, float* __restrict__ Srow) {
  const int r = blockIdx.x;
  const int lane = threadIdx.x;
  const float* src = (r < BATCH) ? (feat + (size_t)r * DIMS)
                                 : (wt + (size_t)(r - BATCH) * DIMS);
  const float4* s4 = (const float4*)src;

  float4 a = s4[lane];        // d = lane*4 .. +3
  float4 c = s4[lane + 64];   // d = 256 + lane*4 .. +3

  float ss = a.x*a.x + a.y*a.y + a.z*a.z + a.w*a.w
           + c.x*c.x + c.y*c.y + c.z*c.z + c.w*c.w;
  float sm = a.x + a.y + a.z + a.w + c.x + c.y + c.z + c.w;
  ss = waveReduceSum(ss);
  sm = waveReduceSum(sm);
  const float rn = 1.f / fmaxf(sqrtf(ss), EPS_NORM);

  ushort4 pa, pc;
  pa.x = f2bf(a.x * rn); pa.y = f2bf(a.y * rn);
  pa.z = f2bf(a.z * rn); pa.w = f2bf(a.w * rn);
  pc.x = f2bf(c.x * rn); pc.y = f2bf(c.y * rn);
  pc.z = f2bf(c.z * rn); pc.w = f2bf(c.w * rn);

  ushort4* dst = (ushort4*)(fnw + (size_t)r * DIMS);
  dst[lane] = pa;          // d = lane*4
  dst[lane + 64] = pc;     // d = 256 + lane*4

  if (lane == 0) Srow[r] = sm * rn;
}

// K2: bf16 MFMA GEMM. dots[1280x256] = fnw[1280x512] . (w rows of fnw)^T.
// One wave per 32x32 tile; grid (40, 8); no LDS; fragments from global (L2-hot).
__global__ __launch_bounds__(64) void k_gemm(
    const unsigned short* __restrict__ fnw, float* __restrict__ dots) {
  const int lane = threadIdx.x;
  const int r0 = blockIdx.x * 32;          // output rows (stacked)
  const int j0 = blockIdx.y * 32;          // class cols

  const int lm = lane & 15;                // row/col within fragment
  const int lk = (lane >> 4) * 8;          // k sub-block (0,8,16,24)

  // A fragment rows
  const unsigned short* arow0 = fnw + (size_t)(r0 + lm) * DIMS + lk;
  const unsigned short* arow1 = fnw + (size_t)(r0 + 16 + lm) * DIMS + lk;
  // B fragment rows: B[k][col] = W[col][k], W rows start at stacked row 1024
  const unsigned short* brow0 = fnw + (size_t)(BATCH + j0 + lm) * DIMS + lk;
  const unsigned short* brow1 = fnw + (size_t)(BATCH + j0 + 16 + lm) * DIMS + lk;

  f32x4 acc00 = {0.f,0.f,0.f,0.f}, acc01 = {0.f,0.f,0.f,0.f};
  f32x4 acc10 = {0.f,0.f,0.f,0.f}, acc11 = {0.f,0.f,0.f,0.f};

#pragma unroll
  for (int k0 = 0; k0 < DIMS; k0 += 32) {
    const bf16x8 a0 = *(const bf16x8*)(arow0 + k0);
    const bf16x8 a1 = *(const bf16x8*)(arow1 + k0);
    const bf16x8 b0 = *(const bf16x8*)(brow0 + k0);
    const bf16x8 b1 = *(const bf16x8*)(brow1 + k0);
    acc00 = __builtin_amdgcn_mfma_f32_16x16x32_bf16(a0, b0, acc00, 0, 0, 0);
    acc01 = __builtin_amdgcn_mfma_f32_16x16x32_bf16(a0, b1, acc01, 0, 0, 0);
    acc10 = __builtin_amdgcn_mfma_f32_16x16x32_bf16(a1, b0, acc10, 0, 0, 0);
    acc11 = __builtin_amdgcn_mfma_f32_16x16x32_bf16(a1, b1, acc11, 0, 0, 0);
  }

  // C/D layout: col = lane&15, row = (lane>>4)*4 + q  (m89-verified)
  const int crow = (lane >> 4) * 4;
  const int ccol = lane & 15;
#pragma unroll
  for (int q = 0; q < 4; ++q) {
    dots[(size_t)(r0 + crow + q) * CLS + (j0 + ccol)]           = acc00[q];
    dots[(size_t)(r0 + crow + q) * CLS + (j0 + 16 + ccol)]      = acc01[q];
    dots[(size_t)(r0 + 16 + crow + q) * CLS + (j0 + ccol)]      = acc10[q];
    dots[(size_t)(r0 + 16 + crow + q) * CLS + (j0 + 16 + ccol)] = acc11[q];
  }
}

// K3: reduce protoc block (stacked rows 1024..1279) to 64 deterministic partials.
// grid = 64, block = 256; each thread one float4 of dots.
__global__ __launch_bounds__(256) void k_red(
    const float* __restrict__ dots, const float* __restrict__ Srow,
    float* __restrict__ partial) {
  const int b = blockIdx.x;
  const int t = threadIdx.x;
  const int g = b * 1024 + t * 4;          // element index within 256x256 block
  const int i = g >> 8;                    // protoc row
  const int j = g & 255;                   // protoc col (j%4==0)

  const float4 d4 = *(const float4*)(dots + (size_t)BATCH * CLS + g);
  const float swi = Srow[BATCH + i];
  const float4 swj = *(const float4*)(Srow + BATCH + j);

  float s = 0.f;
  const float dot[4] = {d4.x, d4.y, d4.z, d4.w};
  const float sw[4] = {swj.x, swj.y, swj.z, swj.w};
#pragma unroll
  for (int e = 0; e < 4; ++e) {
    float dist;
    if (i == j + e) {
      dist = sqrtf(DEPS2);                 // exact diagonal (self-distance)
    } else {
      const float d2 = 2.f - 2.f * dot[e] + 2.f * EPS_PD * (swi - sw[e]) + DEPS2;
      dist = sqrtf(fmaxf(d2, 0.f));
    }
    s += dist;
  }

  __shared__ float red[4];
  float ws = waveReduceSum(s);
  if ((t & 63) == 0) red[t >> 6] = ws;
  __syncthreads();
  if (t == 0) partial[b] = red[0] + red[1] + red[2] + red[3];
}

// K4: epilogue over the 1024x256 main block. grid = 256, block = 256, float4 each.
__global__ __launch_bounds__(256) void k_epi(
    const float* __restrict__ dots, const float* __restrict__ Srow,
    const float* __restrict__ partial, const float* __restrict__ dscale,
    const int* __restrict__ use_ds, float* __restrict__ out) {
  const int t = threadIdx.x;

  __shared__ float sS;
  if (t < 64) {
    float v = partial[t];
    v = waveReduceSum(v);
    if (t == 0) sS = v;
  }
  __syncthreads();
  const float Ssc = 0.1f * sS;
  const float sc = (use_ds[0] != 0) ? fabsf(dscale[0]) : 1.0f;

  const int g = (blockIdx.x * 256 + t) * 4;  // element index within 1024x256
  const int i = g >> 8;                      // feature row
  const int j = g & 255;                     // class col (j%4==0)

  const float4 d4 = *(const float4*)(dots + g);
  const float sfi = Srow[i];
  const float4 swj = *(const float4*)(Srow + BATCH + j);

  const float dot[4] = {d4.x, d4.y, d4.z, d4.w};
  const float sw[4] = {swj.x, swj.y, swj.z, swj.w};
  float4 o;
  float* op = (float*)&o;
#pragma unroll
  for (int e = 0; e < 4; ++e) {
    const float d2 = 2.f - 2.f * dot[e] + 2.f * EPS_PD * (sfi - sw[e]) + DEPS2;
    const float dist = sqrtf(fmaxf(d2, 0.f));
    op[e] = (Ssc - dist) * sc;
  }
  *(float4*)(out + g) = o;
}

extern "C" void kernel_launch(void* const* d_in, const int* in_sizes, int n_in,
                              void* d_out, int out_size, void* d_ws, size_t ws_size,
                              hipStream_t stream) {
  const float* feat = (const float*)d_in[0];     // [1024,512]
  const float* wt   = (const float*)d_in[1];     // [256,512]
  const float* ds   = (const float*)d_in[2];     // [1]
  const int*   use  = (const int*)d_in[3];       // scalar
  float* out = (float*)d_out;                    // [1024,256] fp32

  // ws layout (bytes): fnw bf16 1280*512*2 = 1,310,720 ; then floats
  unsigned short* fnw = (unsigned short*)d_ws;
  float* fbase   = (float*)((char*)d_ws + (size_t)ROWS * DIMS * 2);
  float* Srow    = fbase;                        // 1280
  float* partial = fbase + ROWS;                 // 64
  float* dots    = fbase + ROWS + 64;            // 1280*256 (16B-aligned: offset 1344 floats)

  k_norm<<<ROWS, 64, 0, stream>>>(feat, wt, fnw, Srow);
  k_gemm<<<dim3(ROWS / 32, CLS / 32), 64, 0, stream>>>(fnw, dots);
  k_red<<<64, 256, 0, stream>>>(dots, Srow, partial);
  k_epi<<<256, 256, 0, stream>>>(dots, Srow, partial, ds, use, out);
}